// Round 2
// baseline (192.025 us; speedup 1.0000x reference)
//
#include <hip/hip_runtime.h>

#define DIM 64
#define HID 256           // 4*dim
#define ROWB 512          // bytes per node row: [A(256)|B(256)], perm [m][ct], OFFSET-BINARY u8 (q+127)
#define QSCALE  25.4f     // 127/5  (quantize)
#define DQSCALE (5.0f/127.0f)

typedef short s8v  __attribute__((ext_vector_type(8)));   // 8 bf16 (4 VGPRs)
typedef float f4v  __attribute__((ext_vector_type(4)));   // 4 fp32 acc
typedef float f2v  __attribute__((ext_vector_type(2)));   // packed f32 pair (v_pk_*_f32)
typedef unsigned short u16x2 __attribute__((ext_vector_type(2)));

union U16 { uint4 u; s8v s; };

__device__ __forceinline__ unsigned short bf16_rne(float f) {
    unsigned u = __float_as_uint(f);
    u = (u + 0x7fffu + ((u >> 16) & 1u)) >> 16;
    return (unsigned short)u;
}
__device__ __forceinline__ unsigned pk_bf16(float a, float b) {
    return (unsigned)bf16_rne(a) | ((unsigned)bf16_rne(b) << 16);
}

__device__ __forceinline__ u16x2 as_u16x2(unsigned v) { union { unsigned u; u16x2 s; } c; c.u = v; return c.s; }
__device__ __forceinline__ unsigned as_u32(u16x2 v)   { union { u16x2 s; unsigned u; } c; c.s = v; return c.u; }

// DPP add; after shr1/2/4/8 + row_bcast15(0xa): lane31 = sum(lanes 0..31),
// lane63 = sum(lanes 32..63).
#define DPP_ADD(x, ctrl, rmask)                                               \
    (x) += __int_as_float(__builtin_amdgcn_update_dpp(                        \
        0, __float_as_int(x), (ctrl), (rmask), 0xf, true))

// ---------------------------------------------------------------------------
// Kernel 0: swizzle Wcat = [W1[0:64,:] | W1[64:128,:]] (64 x 512 fp32) into
// bf16 B-fragments for mfma_f32_16x16x32_bf16 (unchanged).
// ---------------------------------------------------------------------------
__global__ __launch_bounds__(256) void prep_wfrag(
    const float* __restrict__ W1, unsigned short* __restrict__ wf)
{
    const int f = blockIdx.x * 256 + threadIdx.x;
    if (f >= 32 * 2 * 64) return;
    const int lane = f & 63;
    const int t    = (f >> 6) & 1;
    const int ct   = f >> 7;
    const int col  = ct * 16 + (lane & 15);
    const int k0   = t * 32 + (lane >> 4) * 8;
    const float* __restrict__ wsrc =
        W1 + ((col >= HID) ? (DIM * HID + col - HID) : col);
    unsigned short v[8];
#pragma unroll
    for (int j = 0; j < 8; ++j) v[j] = bf16_rne(wsrc[(size_t)(k0 + j) * HID]);
    uint4 o;
    o.x = (unsigned)v[0] | ((unsigned)v[1] << 16);
    o.y = (unsigned)v[2] | ((unsigned)v[3] << 16);
    o.z = (unsigned)v[4] | ((unsigned)v[5] << 16);
    o.w = (unsigned)v[6] | ((unsigned)v[7] << 16);
    *(uint4*)(wf + (size_t)f * 8) = o;
}

// ---------------------------------------------------------------------------
// Kernel 1: MFMA node GEMM -> offset-binary u8 table (q+127), static scale,
// permuted layout. Byte (within half) = m*16 + ct  <->  hidden unit
// u = ct*16 + m.
// ---------------------------------------------------------------------------
__global__ __launch_bounds__(256) void node_mfma_q(
    const float* __restrict__ x, const unsigned short* __restrict__ wf,
    const float* __restrict__ b1, unsigned char* __restrict__ tab, int n)
{
    const int lane    = threadIdx.x & 63;
    const int w       = threadIdx.x >> 6;
    const int rowgrp  = w >> 1;
    const int colhalf = w & 1;
    const int m       = lane & 15;
    const int quad    = lane >> 4;
    const int rbase   = blockIdx.x * 32 + rowgrp * 16;

    const int arow = rbase + m;
    const float* __restrict__ xr = x + (size_t)((arow < n) ? arow : (n - 1)) * DIM;
    s8v a[2];
#pragma unroll
    for (int t = 0; t < 2; ++t) {
        const float4 lo = *(const float4*)(xr + t * 32 + quad * 8);
        const float4 hi = *(const float4*)(xr + t * 32 + quad * 8 + 4);
        U16 u;
        u.u.x = pk_bf16(lo.x, lo.y);
        u.u.y = pk_bf16(lo.z, lo.w);
        u.u.z = pk_bf16(hi.x, hi.y);
        u.u.w = pk_bf16(hi.z, hi.w);
        a[t] = u.s;
    }

    const uint4* __restrict__ wfv = (const uint4*)wf;

    f4v acc[16];
#pragma unroll
    for (int ct = 0; ct < 16; ++ct) {
        const int ctg = colhalf * 16 + ct;
        U16 b0u, b1u;
        b0u.u = wfv[(ctg * 2 + 0) * 64 + lane];
        b1u.u = wfv[(ctg * 2 + 1) * 64 + lane];
        f4v c = {0.f, 0.f, 0.f, 0.f};
        c = __builtin_amdgcn_mfma_f32_16x16x32_bf16(a[0], b0u.s, c, 0, 0, 0);
        c = __builtin_amdgcn_mfma_f32_16x16x32_bf16(a[1], b1u.s, c, 0, 0, 0);
        if (colhalf == 0) {
            const float bias = b1[ctg * 16 + m];
            c[0] += bias; c[1] += bias; c[2] += bias; c[3] += bias;
        }
        acc[ct] = c;
    }

    // epilogue: quantize to offset-binary u8 (q+127 in [0,254]), 16 B/row/lane
#pragma unroll
    for (int r = 0; r < 4; ++r) {
        const int gr = rbase + quad * 4 + r;
        if (gr >= n) continue;
        unsigned b[16];
#pragma unroll
        for (int ct = 0; ct < 16; ++ct) {
            float v = __builtin_rintf(acc[ct][r] * QSCALE);
            v = fminf(fmaxf(v, -127.f), 127.f);
            b[ct] = (unsigned)((int)v + 127);
        }
        uint4 o;
        o.x = b[0]  | (b[1]  << 8) | (b[2]  << 16) | (b[3]  << 24);
        o.y = b[4]  | (b[5]  << 8) | (b[6]  << 16) | (b[7]  << 24);
        o.z = b[8]  | (b[9]  << 8) | (b[10] << 16) | (b[11] << 24);
        o.w = b[12] | (b[13] << 8) | (b[14] << 16) | (b[15] << 24);
        *(uint4*)(tab + (size_t)gr * ROWB + colhalf * 256 + m * 16) = o;
    }
}

// ---------------------------------------------------------------------------
// Kernel 2: per-edge MLP tail, packed math.
// 16 B/lane, 2 edges per 32-lane half-wave, 8 edges per wave-iteration.
// Lane (l31 = lane&31): s bytes at 16*l31 (own half), d bytes at 16*(l31^16)
// (opposite half) -> lanes 0..15 of a group do dir-1, 16..31 do dir-2.
// Table is offset-binary: b_a + b_b = t + 254 (u16);
// relu(t) = usub_sat(b_a + b_b, 254)   -- exact integer in [0,254].
// u16 -> f32 via v_cvt_f32_ubyte0/2 (value fits in low byte) -- EXACT, no
// big-offset cancellation. Matches round-0 arithmetic bit-for-bit in error
// behavior (same quantization, same f32 weights).
// ---------------------------------------------------------------------------
__device__ __forceinline__ float pass_dot(const uint4 S, const uint4 D,
                                          const f2v* __restrict__ w)
{
    const unsigned sa[4] = {S.x, S.y, S.z, S.w};
    const unsigned da[4] = {D.x, D.y, D.z, D.w};
    const u16x2 k254 = {254, 254};
    f2v acc; acc.x = 0.f; acc.y = 0.f;
#pragma unroll
    for (int i = 0; i < 4; ++i) {
        // zero-extend byte pairs (b0,b1) and (b2,b3) to u16x2 (sel 12 = 0x00)
        const unsigned zs0 = __builtin_amdgcn_perm(0u, sa[i], 0x0C010C00u);
        const unsigned zs1 = __builtin_amdgcn_perm(0u, sa[i], 0x0C030C02u);
        const unsigned zd0 = __builtin_amdgcn_perm(0u, da[i], 0x0C010C00u);
        const unsigned zd1 = __builtin_amdgcn_perm(0u, da[i], 0x0C030C02u);
        // relu in u16 domain: one v_pk_sub_u16 (clamp) each
        const unsigned r0 = as_u32(__builtin_elementwise_sub_sat(
                                as_u16x2(zs0) + as_u16x2(zd0), k254));
        const unsigned r1 = as_u32(__builtin_elementwise_sub_sat(
                                as_u16x2(zs1) + as_u16x2(zd1), k254));
        // exact small-int converts: v_cvt_f32_ubyte0 / ubyte2
        f2v f0, f1;
        f0.x = (float)(r0 & 0xffu);
        f0.y = (float)((r0 >> 16) & 0xffu);
        f1.x = (float)(r1 & 0xffu);
        f1.y = (float)((r1 >> 16) & 0xffu);
        acc = f0 * w[2 * i] + acc;        // v_pk_fma_f32
        acc = f1 * w[2 * i + 1] + acc;
    }
    return acc.x + acc.y;
}

__global__ __launch_bounds__(256, 8) void edge_mlp_q(
    const int* __restrict__ ei, const unsigned char* __restrict__ tab,
    const float* __restrict__ W2, const float* __restrict__ b2,
    float* __restrict__ out, int ne)
{
    const int lane = threadIdx.x & 63;
    const int l31  = lane & 31;
    const int m    = lane & 15;
    const bool hi  = lane >= 32;

    // per-lane weights: byte j of the 16-B chunk <-> unit u = j*16 + m.
    // pairs follow the zext pairing (b0,b1),(b2,b3).
    f2v w[8];
#pragma unroll
    for (int i = 0; i < 4; ++i) {
        f2v w0, w1;
        w0.x = W2[(4 * i + 0) * 16 + m]; w0.y = W2[(4 * i + 1) * 16 + m];
        w1.x = W2[(4 * i + 2) * 16 + m]; w1.y = W2[(4 * i + 3) * 16 + m];
        w[2 * i] = w0; w[2 * i + 1] = w1;
    }
    const float bias = b2[0];
    const float sc   = 0.5f * DQSCALE;

    const unsigned offS = 16u * (unsigned)l31;
    const unsigned offD = 16u * (unsigned)(l31 ^ 16);

    // statically balanced partition over groups of 8 edges; 2048 blocks
    // (8 blocks/CU, all-resident) -> no grid-stride tail imbalance.
    const int wflat = __builtin_amdgcn_readfirstlane(
        (int)(blockIdx.x * 4 + (threadIdx.x >> 6)));
    const int nw = (int)gridDim.x * 4;
    const int ng = ne >> 3;
    const int gq = ng / nw, gr = ng % nw;
    int g        = wflat * gq + (wflat < gr ? wflat : gr);
    const int ge = g + gq + (wflat < gr ? 1 : 0);

    for (; g < ge; ++g) {
        const int e0 = __builtin_amdgcn_readfirstlane(g << 3);
        int se[8], de[8];
#pragma unroll
        for (int i = 0; i < 8; ++i) {      // contiguous + uniform -> s_loads
            se[i] = ei[e0 + i];
            de[i] = ei[ne + e0 + i];
        }

        uint4 S, D, Sn, Dn;
        {
            const unsigned vs = ((unsigned)(hi ? se[1] : se[0]) << 9) + offS;
            const unsigned vd = ((unsigned)(hi ? de[1] : de[0]) << 9) + offD;
            S = *(const uint4*)(tab + vs);
            D = *(const uint4*)(tab + vd);
        }
#pragma unroll
        for (int p = 0; p < 4; ++p) {
            if (p < 3) {                   // prefetch next pass's rows
                const unsigned vs = ((unsigned)(hi ? se[2*p+3] : se[2*p+2]) << 9) + offS;
                const unsigned vd = ((unsigned)(hi ? de[2*p+3] : de[2*p+2]) << 9) + offD;
                Sn = *(const uint4*)(tab + vs);
                Dn = *(const uint4*)(tab + vd);
            }
            float s = pass_dot(S, D, w);
            DPP_ADD(s, 0x111, 0xf);
            DPP_ADD(s, 0x112, 0xf);
            DPP_ADD(s, 0x114, 0xf);
            DPP_ADD(s, 0x118, 0xf);
            DPP_ADD(s, 0x142, 0xa);        // lane31/lane63 = per-edge sums
            if (l31 == 31) out[e0 + 2 * p + (lane >> 5)] = fmaf(sc, s, bias);
            S = Sn; D = Dn;
        }
    }

    // tail (ne % 8 edges) -- dead for ne = 500000, kept for safety
    const int rem = ne & 7;
    if (rem && wflat == 0) {
        const int base = ne & ~7;
#pragma unroll
        for (int p = 0; p < 4; ++p) {
            const int eA = base + 2 * p;
            if (eA < ne) {
                const int eB = (eA + 1 < ne) ? eA + 1 : eA;
                const unsigned vs = ((unsigned)(hi ? ei[eB] : ei[eA]) << 9) + offS;
                const unsigned vd = ((unsigned)(hi ? ei[ne + eB] : ei[ne + eA]) << 9) + offD;
                const uint4 St = *(const uint4*)(tab + vs);
                const uint4 Dt = *(const uint4*)(tab + vd);
                float s = pass_dot(St, Dt, w);
                DPP_ADD(s, 0x111, 0xf);
                DPP_ADD(s, 0x112, 0xf);
                DPP_ADD(s, 0x114, 0xf);
                DPP_ADD(s, 0x118, 0xf);
                DPP_ADD(s, 0x142, 0xa);
                const int e = eA + (lane >> 5);
                if (l31 == 31 && e < ne) out[e] = fmaf(sc, s, bias);
            }
        }
    }
}

// ---------------------------------------------------------------------------
// Inputs: 0:x[N,64] f32  1:edge_index3[2,E] i32  2,3: edge_attr (unused)
//         4: batch (unused)  5:W1[128,256] 6:b1[256] 7:W2[256,1] 8:b2[1]
// Output: [E] f32.
// Workspace: tab = N*512 u8 (25.6 MB), then wf = 64 KB W-fragments.
// ---------------------------------------------------------------------------
extern "C" void kernel_launch(void* const* d_in, const int* in_sizes, int n_in,
                              void* d_out, int out_size, void* d_ws, size_t ws_size,
                              hipStream_t stream) {
    const float* x  = (const float*)d_in[0];
    const int*   ei = (const int*)d_in[1];
    const float* W1 = (const float*)d_in[5];
    const float* b1 = (const float*)d_in[6];
    const float* W2 = (const float*)d_in[7];
    const float* b2 = (const float*)d_in[8];
    float* out = (float*)d_out;

    const int n  = in_sizes[0] / DIM;  // 50000 nodes
    const int ne = in_sizes[1] / 2;    // 500000 edges

    unsigned char*  tab = (unsigned char*)d_ws;             // [n,512] u8
    unsigned short* wf  = (unsigned short*)(tab + (size_t)n * ROWB);

    prep_wfrag<<<16, 256, 0, stream>>>(W1, wf);
    node_mfma_q<<<(n + 31) / 32, 256, 0, stream>>>(x, wf, b1, tab, n);
    edge_mlp_q<<<2048, 256, 0, stream>>>(ei, tab, W2, b2, out, ne);
}

// Round 3
// 187.288 us; speedup vs baseline: 1.0253x; 1.0253x over previous
//
#include <hip/hip_runtime.h>

#define DIM 64
#define HID 256           // 4*dim
#define ROWB 512          // bytes per node row: [A(256)|B(256)], perm [m][ct], OFFSET-BINARY u8 (q+127)
#define QSCALE  25.4f     // 127/5  (quantize)
#define DQSCALE (5.0f/127.0f)

typedef short s8v  __attribute__((ext_vector_type(8)));   // 8 bf16 (4 VGPRs)
typedef float f4v  __attribute__((ext_vector_type(4)));   // 4 fp32 acc
typedef float f2v  __attribute__((ext_vector_type(2)));   // packed f32 pair (v_pk_*_f32)
typedef unsigned short u16x2 __attribute__((ext_vector_type(2)));

union U16 { uint4 u; s8v s; };

__device__ __forceinline__ unsigned short bf16_rne(float f) {
    unsigned u = __float_as_uint(f);
    u = (u + 0x7fffu + ((u >> 16) & 1u)) >> 16;
    return (unsigned short)u;
}
__device__ __forceinline__ unsigned pk_bf16(float a, float b) {
    return (unsigned)bf16_rne(a) | ((unsigned)bf16_rne(b) << 16);
}

__device__ __forceinline__ u16x2 as_u16x2(unsigned v) { union { unsigned u; u16x2 s; } c; c.u = v; return c.s; }
__device__ __forceinline__ unsigned as_u32(u16x2 v)   { union { u16x2 s; unsigned u; } c; c.s = v; return c.u; }

// DPP add; after shr1/2/4/8 + row_bcast15(0xa): lane31 = sum(lanes 0..31),
// lane63 = sum(lanes 32..63).
#define DPP_ADD(x, ctrl, rmask)                                               \
    (x) += __int_as_float(__builtin_amdgcn_update_dpp(                        \
        0, __float_as_int(x), (ctrl), (rmask), 0xf, true))

// ---------------------------------------------------------------------------
// Kernel 0: swizzle Wcat = [W1[0:64,:] | W1[64:128,:]] (64 x 512 fp32) into
// bf16 B-fragments for mfma_f32_16x16x32_bf16 (unchanged).
// ---------------------------------------------------------------------------
__global__ __launch_bounds__(256) void prep_wfrag(
    const float* __restrict__ W1, unsigned short* __restrict__ wf)
{
    const int f = blockIdx.x * 256 + threadIdx.x;
    if (f >= 32 * 2 * 64) return;
    const int lane = f & 63;
    const int t    = (f >> 6) & 1;
    const int ct   = f >> 7;
    const int col  = ct * 16 + (lane & 15);
    const int k0   = t * 32 + (lane >> 4) * 8;
    const float* __restrict__ wsrc =
        W1 + ((col >= HID) ? (DIM * HID + col - HID) : col);
    unsigned short v[8];
#pragma unroll
    for (int j = 0; j < 8; ++j) v[j] = bf16_rne(wsrc[(size_t)(k0 + j) * HID]);
    uint4 o;
    o.x = (unsigned)v[0] | ((unsigned)v[1] << 16);
    o.y = (unsigned)v[2] | ((unsigned)v[3] << 16);
    o.z = (unsigned)v[4] | ((unsigned)v[5] << 16);
    o.w = (unsigned)v[6] | ((unsigned)v[7] << 16);
    *(uint4*)(wf + (size_t)f * 8) = o;
}

// ---------------------------------------------------------------------------
// Kernel 1: MFMA node GEMM -> offset-binary u8 table (q+127), static scale,
// permuted layout. Byte (within half) = m*16 + ct  <->  hidden unit
// u = ct*16 + m.
// ---------------------------------------------------------------------------
__global__ __launch_bounds__(256) void node_mfma_q(
    const float* __restrict__ x, const unsigned short* __restrict__ wf,
    const float* __restrict__ b1, unsigned char* __restrict__ tab, int n)
{
    const int lane    = threadIdx.x & 63;
    const int w       = threadIdx.x >> 6;
    const int rowgrp  = w >> 1;
    const int colhalf = w & 1;
    const int m       = lane & 15;
    const int quad    = lane >> 4;
    const int rbase   = blockIdx.x * 32 + rowgrp * 16;

    const int arow = rbase + m;
    const float* __restrict__ xr = x + (size_t)((arow < n) ? arow : (n - 1)) * DIM;
    s8v a[2];
#pragma unroll
    for (int t = 0; t < 2; ++t) {
        const float4 lo = *(const float4*)(xr + t * 32 + quad * 8);
        const float4 hi = *(const float4*)(xr + t * 32 + quad * 8 + 4);
        U16 u;
        u.u.x = pk_bf16(lo.x, lo.y);
        u.u.y = pk_bf16(lo.z, lo.w);
        u.u.z = pk_bf16(hi.x, hi.y);
        u.u.w = pk_bf16(hi.z, hi.w);
        a[t] = u.s;
    }

    const uint4* __restrict__ wfv = (const uint4*)wf;

    f4v acc[16];
#pragma unroll
    for (int ct = 0; ct < 16; ++ct) {
        const int ctg = colhalf * 16 + ct;
        U16 b0u, b1u;
        b0u.u = wfv[(ctg * 2 + 0) * 64 + lane];
        b1u.u = wfv[(ctg * 2 + 1) * 64 + lane];
        f4v c = {0.f, 0.f, 0.f, 0.f};
        c = __builtin_amdgcn_mfma_f32_16x16x32_bf16(a[0], b0u.s, c, 0, 0, 0);
        c = __builtin_amdgcn_mfma_f32_16x16x32_bf16(a[1], b1u.s, c, 0, 0, 0);
        if (colhalf == 0) {
            const float bias = b1[ctg * 16 + m];
            c[0] += bias; c[1] += bias; c[2] += bias; c[3] += bias;
        }
        acc[ct] = c;
    }

    // epilogue: quantize to offset-binary u8 (q+127 in [0,254]), 16 B/row/lane
#pragma unroll
    for (int r = 0; r < 4; ++r) {
        const int gr = rbase + quad * 4 + r;
        if (gr >= n) continue;
        unsigned b[16];
#pragma unroll
        for (int ct = 0; ct < 16; ++ct) {
            float v = __builtin_rintf(acc[ct][r] * QSCALE);
            v = fminf(fmaxf(v, -127.f), 127.f);
            b[ct] = (unsigned)((int)v + 127);
        }
        uint4 o;
        o.x = b[0]  | (b[1]  << 8) | (b[2]  << 16) | (b[3]  << 24);
        o.y = b[4]  | (b[5]  << 8) | (b[6]  << 16) | (b[7]  << 24);
        o.z = b[8]  | (b[9]  << 8) | (b[10] << 16) | (b[11] << 24);
        o.w = b[12] | (b[13] << 8) | (b[14] << 16) | (b[15] << 24);
        *(uint4*)(tab + (size_t)gr * ROWB + colhalf * 256 + m * 16) = o;
    }
}

// ---------------------------------------------------------------------------
// Kernel 2: per-edge MLP tail. 16 B/lane, 2 edges per 32-lane half-wave,
// 8 edges per wave-iteration with ALL 8 dwordx4 table loads issued up front
// (8 KB/wave in flight -> latency coverage); next iteration's indices
// prefetched during compute; 4 output stores batched at iteration end
// (avoids the round-2 write amplification).
// Table is offset-binary: relu(t) = usub_sat(b_a + b_b, 254) -- exact int
// in [0,254]; converts via v_cvt_f32_ubyte0/2 (exact).
// ---------------------------------------------------------------------------
__device__ __forceinline__ float pass_dot(const uint4 S, const uint4 D,
                                          const f2v* __restrict__ w)
{
    const unsigned sa[4] = {S.x, S.y, S.z, S.w};
    const unsigned da[4] = {D.x, D.y, D.z, D.w};
    const u16x2 k254 = {254, 254};
    f2v acc; acc.x = 0.f; acc.y = 0.f;
#pragma unroll
    for (int i = 0; i < 4; ++i) {
        // zero-extend byte pairs (b0,b1) and (b2,b3) to u16x2 (sel 12 = 0x00)
        const unsigned zs0 = __builtin_amdgcn_perm(0u, sa[i], 0x0C010C00u);
        const unsigned zs1 = __builtin_amdgcn_perm(0u, sa[i], 0x0C030C02u);
        const unsigned zd0 = __builtin_amdgcn_perm(0u, da[i], 0x0C010C00u);
        const unsigned zd1 = __builtin_amdgcn_perm(0u, da[i], 0x0C030C02u);
        // relu in u16 domain: one v_pk_sub_u16 (clamp) each
        const unsigned r0 = as_u32(__builtin_elementwise_sub_sat(
                                as_u16x2(zs0) + as_u16x2(zd0), k254));
        const unsigned r1 = as_u32(__builtin_elementwise_sub_sat(
                                as_u16x2(zs1) + as_u16x2(zd1), k254));
        // exact small-int converts: v_cvt_f32_ubyte0 / ubyte2
        f2v f0, f1;
        f0.x = (float)(r0 & 0xffu);
        f0.y = (float)((r0 >> 16) & 0xffu);
        f1.x = (float)(r1 & 0xffu);
        f1.y = (float)((r1 >> 16) & 0xffu);
        acc = f0 * w[2 * i] + acc;        // v_pk_fma_f32
        acc = f1 * w[2 * i + 1] + acc;
    }
    return acc.x + acc.y;
}

__global__ __launch_bounds__(256, 8) void edge_mlp_q(
    const int* __restrict__ ei, const unsigned char* __restrict__ tab,
    const float* __restrict__ W2, const float* __restrict__ b2,
    float* __restrict__ out, int ne)
{
    const int lane = threadIdx.x & 63;
    const int l31  = lane & 31;
    const int m    = lane & 15;
    const bool hi  = lane >= 32;

    // per-lane weights: byte j of the 16-B chunk <-> unit u = j*16 + m.
    // pairs follow the zext pairing (b0,b1),(b2,b3).
    f2v w[8];
#pragma unroll
    for (int i = 0; i < 4; ++i) {
        f2v w0, w1;
        w0.x = W2[(4 * i + 0) * 16 + m]; w0.y = W2[(4 * i + 1) * 16 + m];
        w1.x = W2[(4 * i + 2) * 16 + m]; w1.y = W2[(4 * i + 3) * 16 + m];
        w[2 * i] = w0; w[2 * i + 1] = w1;
    }
    const float bias = b2[0];
    const float sc   = 0.5f * DQSCALE;

    const unsigned offS = 16u * (unsigned)l31;
    const unsigned offD = 16u * (unsigned)(l31 ^ 16);

    // statically balanced partition over groups of 8 edges; 2048 blocks
    // (8 blocks/CU, all-resident).
    const int wflat = __builtin_amdgcn_readfirstlane(
        (int)(blockIdx.x * 4 + (threadIdx.x >> 6)));
    const int nw = (int)gridDim.x * 4;
    const int ng = ne >> 3;
    const int gq = ng / nw, gr = ng % nw;
    int g        = wflat * gq + (wflat < gr ? wflat : gr);
    const int ge = g + gq + (wflat < gr ? 1 : 0);

    if (g < ge) {
        // prologue: indices of the first group (uniform -> SGPRs)
        int se[8], de[8];
        {
            const int e0 = __builtin_amdgcn_readfirstlane(g << 3);
#pragma unroll
            for (int i = 0; i < 8; ++i) {
                se[i] = ei[e0 + i];
                de[i] = ei[ne + e0 + i];
            }
        }

        for (; g < ge; ++g) {
            const int e0 = __builtin_amdgcn_readfirstlane(g << 3);

            // ---- issue ALL 8 table loads up front (8 KB/wave in flight) ----
            uint4 T[8];
#pragma unroll
            for (int p = 0; p < 4; ++p) {
                const unsigned vs = ((unsigned)(hi ? se[2*p+1] : se[2*p]) << 9) + offS;
                const unsigned vd = ((unsigned)(hi ? de[2*p+1] : de[2*p]) << 9) + offD;
                T[2*p]     = *(const uint4*)(tab + vs);
                T[2*p + 1] = *(const uint4*)(tab + vd);
            }

            // ---- prefetch next group's indices (hidden under compute) ----
            int sen[8], den[8];
            {
                const int gn = (g + 1 < ge) ? (g + 1) : g;   // clamp: stay in-bounds
                const int e1 = __builtin_amdgcn_readfirstlane(gn << 3);
#pragma unroll
                for (int i = 0; i < 8; ++i) {
                    sen[i] = ei[e1 + i];
                    den[i] = ei[ne + e1 + i];
                }
            }

            // ---- compute 4 passes ----
            float r[4];
#pragma unroll
            for (int p = 0; p < 4; ++p) {
                float s = pass_dot(T[2*p], T[2*p + 1], w);
                DPP_ADD(s, 0x111, 0xf);
                DPP_ADD(s, 0x112, 0xf);
                DPP_ADD(s, 0x114, 0xf);
                DPP_ADD(s, 0x118, 0xf);
                DPP_ADD(s, 0x142, 0xa);    // lane31/lane63 = per-edge sums
                r[p] = s;
            }

            // ---- batched stores: 4 back-to-back 8-B stores (2 lanes each) ----
            if (l31 == 31) {
                const int eo = e0 + (lane >> 5);
                out[eo]     = fmaf(sc, r[0], bias);
                out[eo + 2] = fmaf(sc, r[1], bias);
                out[eo + 4] = fmaf(sc, r[2], bias);
                out[eo + 6] = fmaf(sc, r[3], bias);
            }

#pragma unroll
            for (int i = 0; i < 8; ++i) { se[i] = sen[i]; de[i] = den[i]; }
        }
    }

    // tail (ne % 8 edges) -- dead for ne = 500000, kept for safety
    const int rem = ne & 7;
    if (rem && wflat == 0) {
        const int base = ne & ~7;
#pragma unroll
        for (int p = 0; p < 4; ++p) {
            const int eA = base + 2 * p;
            if (eA < ne) {
                const int eB = (eA + 1 < ne) ? eA + 1 : eA;
                const unsigned vs = ((unsigned)(hi ? ei[eB] : ei[eA]) << 9) + offS;
                const unsigned vd = ((unsigned)(hi ? ei[ne + eB] : ei[ne + eA]) << 9) + offD;
                const uint4 St = *(const uint4*)(tab + vs);
                const uint4 Dt = *(const uint4*)(tab + vd);
                float s = pass_dot(St, Dt, w);
                DPP_ADD(s, 0x111, 0xf);
                DPP_ADD(s, 0x112, 0xf);
                DPP_ADD(s, 0x114, 0xf);
                DPP_ADD(s, 0x118, 0xf);
                DPP_ADD(s, 0x142, 0xa);
                const int e = eA + (lane >> 5);
                if (l31 == 31 && e < ne) out[e] = fmaf(sc, s, bias);
            }
        }
    }
}

// ---------------------------------------------------------------------------
// Inputs: 0:x[N,64] f32  1:edge_index3[2,E] i32  2,3: edge_attr (unused)
//         4: batch (unused)  5:W1[128,256] 6:b1[256] 7:W2[256,1] 8:b2[1]
// Output: [E] f32.
// Workspace: tab = N*512 u8 (25.6 MB), then wf = 64 KB W-fragments.
// ---------------------------------------------------------------------------
extern "C" void kernel_launch(void* const* d_in, const int* in_sizes, int n_in,
                              void* d_out, int out_size, void* d_ws, size_t ws_size,
                              hipStream_t stream) {
    const float* x  = (const float*)d_in[0];
    const int*   ei = (const int*)d_in[1];
    const float* W1 = (const float*)d_in[5];
    const float* b1 = (const float*)d_in[6];
    const float* W2 = (const float*)d_in[7];
    const float* b2 = (const float*)d_in[8];
    float* out = (float*)d_out;

    const int n  = in_sizes[0] / DIM;  // 50000 nodes
    const int ne = in_sizes[1] / 2;    // 500000 edges

    unsigned char*  tab = (unsigned char*)d_ws;             // [n,512] u8
    unsigned short* wf  = (unsigned short*)(tab + (size_t)n * ROWB);

    prep_wfrag<<<16, 256, 0, stream>>>(W1, wf);
    node_mfma_q<<<(n + 31) / 32, 256, 0, stream>>>(x, wf, b1, tab, n);
    edge_mlp_q<<<2048, 256, 0, stream>>>(ei, tab, W2, b2, out, ne);
}